// Round 5
// baseline (194.476 us; speedup 1.0000x reference)
//
#include <hip/hip_runtime.h>
#include <hip/hip_bf16.h>

// Problem constants (match reference)
#define WORLD   4
#define S_SEEDS 16000
#define FANOUT  16
#define F_FRONT (S_SEEDS * (FANOUT + 1))   // 272000 frontier rows / partition
#define E_EDGES (S_SEEDS * FANOUT)         // 256000 edges / partition
#define D       128
#define M_ROWS  (WORLD * S_SEEDS)          // 64000 output rows
#define N_EDGES (WORLD * E_EDGES)          // 1024000 edges total
#define CAP     64                         // per-dst bucket capacity (Poisson(16): P(>64)~3e-20)

typedef __attribute__((ext_vector_type(8))) short bf16x8;
typedef __attribute__((ext_vector_type(4))) float f32x4;
typedef __attribute__((ext_vector_type(4))) unsigned short u16x4;

__device__ __forceinline__ unsigned short f2bf(float f) {
    union { float f; unsigned u; } v; v.f = f;
    unsigned r = v.u + 0x7FFFu + ((v.u >> 16) & 1u);   // RNE
    return (unsigned short)(r >> 16);
}

// ---------------------------------------------------------------------------
// Kernel 1a: bucket fill. 4 edges per thread via int4; one int atomic per
// edge gets the slot. E_EDGES % 4 == 0 so all 4 edges share one partition.
// ---------------------------------------------------------------------------
__global__ __launch_bounds__(256) void fill_k(
    const int* __restrict__ coo_row,
    const int* __restrict__ coo_col,
    int*       __restrict__ cnt,
    int*       __restrict__ elist)
{
    unsigned q = blockIdx.x * 256u + threadIdx.x;     // quad id
    unsigned e = q * 4u;
    unsigned part = e / E_EDGES;                       // same for all 4
    int4 r4 = reinterpret_cast<const int4*>(coo_row)[q];
    int4 c4 = reinterpret_cast<const int4*>(coo_col)[q];
    const unsigned dbase = part * S_SEEDS;
    const unsigned sbase = part * F_FRONT;

    {
        unsigned dst = dbase + (unsigned)r4.x;
        int slot = atomicAdd(&cnt[dst], 1);
        if (slot < CAP) elist[(unsigned long)dst * CAP + slot] = (int)(sbase + c4.x);
    }
    {
        unsigned dst = dbase + (unsigned)r4.y;
        int slot = atomicAdd(&cnt[dst], 1);
        if (slot < CAP) elist[(unsigned long)dst * CAP + slot] = (int)(sbase + c4.y);
    }
    {
        unsigned dst = dbase + (unsigned)r4.z;
        int slot = atomicAdd(&cnt[dst], 1);
        if (slot < CAP) elist[(unsigned long)dst * CAP + slot] = (int)(sbase + c4.z);
    }
    {
        unsigned dst = dbase + (unsigned)r4.w;
        int slot = atomicAdd(&cnt[dst], 1);
        if (slot < CAP) elist[(unsigned long)dst * CAP + slot] = (int)(sbase + c4.w);
    }
}

// ---------------------------------------------------------------------------
// Kernel 1b: per-dst gather (round-3 variant — best measured). Half-wave
// (32 lanes) per dst row; lane owns a fixed float4 channel slice. Indices
// prefetched via int4; chunks of 16 independent row loads. Mean written as
// bf16 (halves h traffic).
// ---------------------------------------------------------------------------
__global__ __launch_bounds__(256) void gather_k(
    const float* __restrict__ feat,
    const int*   __restrict__ cnt,
    const int*   __restrict__ elist,
    unsigned short* __restrict__ hb)   // [M_ROWS][D] bf16
{
    const int t   = threadIdx.x;
    const int dst = blockIdx.x * 8 + (t >> 5);
    const int l   = t & 31;

    int deg = cnt[dst];
    if (deg > CAP) deg = CAP;   // safety (never expected)
    const int* el = elist + (long)dst * CAP;
    const float4* F4 = reinterpret_cast<const float4*>(feat);

    f32x4 accA = {0.f, 0.f, 0.f, 0.f};
    f32x4 accB = {0.f, 0.f, 0.f, 0.f};

    int e = 0;
    for (; e + 16 <= deg; e += 16) {
        int4 i0 = *reinterpret_cast<const int4*>(el + e);
        int4 i1 = *reinterpret_cast<const int4*>(el + e + 4);
        int4 i2 = *reinterpret_cast<const int4*>(el + e + 8);
        int4 i3 = *reinterpret_cast<const int4*>(el + e + 12);
        float4 v0  = F4[(long)i0.x * 32 + l];
        float4 v1  = F4[(long)i0.y * 32 + l];
        float4 v2  = F4[(long)i0.z * 32 + l];
        float4 v3  = F4[(long)i0.w * 32 + l];
        float4 v4  = F4[(long)i1.x * 32 + l];
        float4 v5  = F4[(long)i1.y * 32 + l];
        float4 v6  = F4[(long)i1.z * 32 + l];
        float4 v7  = F4[(long)i1.w * 32 + l];
        float4 v8  = F4[(long)i2.x * 32 + l];
        float4 v9  = F4[(long)i2.y * 32 + l];
        float4 v10 = F4[(long)i2.z * 32 + l];
        float4 v11 = F4[(long)i2.w * 32 + l];
        float4 v12 = F4[(long)i3.x * 32 + l];
        float4 v13 = F4[(long)i3.y * 32 + l];
        float4 v14 = F4[(long)i3.z * 32 + l];
        float4 v15 = F4[(long)i3.w * 32 + l];
        accA[0] += v0.x + v2.x + v4.x + v6.x + v8.x + v10.x + v12.x + v14.x;
        accA[1] += v0.y + v2.y + v4.y + v6.y + v8.y + v10.y + v12.y + v14.y;
        accA[2] += v0.z + v2.z + v4.z + v6.z + v8.z + v10.z + v12.z + v14.z;
        accA[3] += v0.w + v2.w + v4.w + v6.w + v8.w + v10.w + v12.w + v14.w;
        accB[0] += v1.x + v3.x + v5.x + v7.x + v9.x + v11.x + v13.x + v15.x;
        accB[1] += v1.y + v3.y + v5.y + v7.y + v9.y + v11.y + v13.y + v15.y;
        accB[2] += v1.z + v3.z + v5.z + v7.z + v9.z + v11.z + v13.z + v15.z;
        accB[3] += v1.w + v3.w + v5.w + v7.w + v9.w + v11.w + v13.w + v15.w;
    }
    for (; e + 4 <= deg; e += 4) {
        int4 i0 = *reinterpret_cast<const int4*>(el + e);
        float4 v0 = F4[(long)i0.x * 32 + l];
        float4 v1 = F4[(long)i0.y * 32 + l];
        float4 v2 = F4[(long)i0.z * 32 + l];
        float4 v3 = F4[(long)i0.w * 32 + l];
        accA[0] += v0.x + v2.x; accA[1] += v0.y + v2.y;
        accA[2] += v0.z + v2.z; accA[3] += v0.w + v2.w;
        accB[0] += v1.x + v3.x; accB[1] += v1.y + v3.y;
        accB[2] += v1.z + v3.z; accB[3] += v1.w + v3.w;
    }
    for (; e < deg; ++e) {
        float4 v = F4[(long)el[e] * 32 + l];
        accA[0] += v.x; accA[1] += v.y; accA[2] += v.z; accA[3] += v.w;
    }

    u16x4 r;
    r.x = f2bf((accA[0] + accB[0]) * (1.0f / FANOUT));
    r.y = f2bf((accA[1] + accB[1]) * (1.0f / FANOUT));
    r.z = f2bf((accA[2] + accB[2]) * (1.0f / FANOUT));
    r.w = f2bf((accA[3] + accB[3]) * (1.0f / FANOUT));
    *reinterpret_cast<u16x4*>(hb + (long)dst * D + l * 4) = r;
}

// ---------------------------------------------------------------------------
// Kernel 2: fused finish, single-pass (64 rows/block, grid 1000):
//   out[r] = hb[r] @ Wn^T + feat_dst[r] @ Ws^T + b
// GEMM: [M x 256] @ [256 x 128] via mfma_f32_16x16x32_bf16.
// ---------------------------------------------------------------------------
__global__ __launch_bounds__(256) void finish_k(
    const float*          __restrict__ feat,
    const unsigned short* __restrict__ hb,
    const float*          __restrict__ wn,
    const float*          __restrict__ wself,
    const float*          __restrict__ bias,
    float*                __restrict__ out)
{
    // [kstep 8][ctile 8][lane 64] -> one 16B bf16x8 B-fragment per entry
    __shared__ uint4 wlds[8 * 8 * 64];

    const int t = threadIdx.x;

    // ---- stage weights: global fp32 -> bf16 fragments in LDS ----
    for (int idx = t; idx < 8 * 8 * 64; idx += 256) {
        int l  = idx & 63;
        int c  = (idx >> 6) & 7;
        int s  = idx >> 9;
        int o  = c * 16 + (l & 15);          // output channel (B col)
        int kb = s * 32 + (l >> 4) * 8;      // k base (8 contiguous k per lane)
        const float* src = (kb < 128) ? (wn + o * 128 + kb)
                                      : (wself + o * 128 + (kb - 128));
        float4 p0 = reinterpret_cast<const float4*>(src)[0];
        float4 p1 = reinterpret_cast<const float4*>(src)[1];
        uint4 w;
        w.x = (unsigned)f2bf(p0.x) | ((unsigned)f2bf(p0.y) << 16);
        w.y = (unsigned)f2bf(p0.z) | ((unsigned)f2bf(p0.w) << 16);
        w.z = (unsigned)f2bf(p1.x) | ((unsigned)f2bf(p1.y) << 16);
        w.w = (unsigned)f2bf(p1.z) | ((unsigned)f2bf(p1.w) << 16);
        wlds[idx] = w;
    }
    __syncthreads();

    const int wave = t >> 6;
    const int l    = t & 63;
    const int l15  = l & 15;
    const int lhi  = l >> 4;

    const int rowbase = blockIdx.x * 64 + wave * 16;
    const int arow    = rowbase + l15;          // A row this lane loads

    const unsigned short* hrow = hb + (long)arow * D + lhi * 8;
    int part = arow / S_SEEDS;
    int idx  = arow - part * S_SEEDS;
    const float* xrow = feat + ((long)part * F_FRONT + idx) * D + lhi * 8;

    f32x4 acc[8] = {};

#pragma unroll
    for (int s = 0; s < 8; ++s) {
        bf16x8 af;
        if (s < 4) {
            af = *reinterpret_cast<const bf16x8*>(hrow + s * 32);
        } else {
            const float* asrc = xrow + (s - 4) * 32;
            float4 a0 = reinterpret_cast<const float4*>(asrc)[0];
            float4 a1 = reinterpret_cast<const float4*>(asrc)[1];
            af[0] = (short)f2bf(a0.x);
            af[1] = (short)f2bf(a0.y);
            af[2] = (short)f2bf(a0.z);
            af[3] = (short)f2bf(a0.w);
            af[4] = (short)f2bf(a1.x);
            af[5] = (short)f2bf(a1.y);
            af[6] = (short)f2bf(a1.z);
            af[7] = (short)f2bf(a1.w);
        }
#pragma unroll
        for (int c = 0; c < 8; ++c) {
            bf16x8 bf = *reinterpret_cast<const bf16x8*>(&wlds[(s * 8 + c) * 64 + l]);
            acc[c] = __builtin_amdgcn_mfma_f32_16x16x32_bf16(af, bf, acc[c], 0, 0, 0);
        }
    }

    // C/D layout (verified m89): col = lane&15, row = (lane>>4)*4 + reg
#pragma unroll
    for (int c = 0; c < 8; ++c) {
        const int col = c * 16 + l15;
        const float bv = bias[col];
#pragma unroll
        for (int j = 0; j < 4; ++j) {
            const int r = rowbase + lhi * 4 + j;
            out[(long)r * D + col] = acc[c][j] + bv;
        }
    }
}

// ---------------------------------------------------------------------------
// Fallback finish (in-place h in d_out as f32), for small-ws path.
// ---------------------------------------------------------------------------
__global__ __launch_bounds__(256) void finish_f32_k(
    const float* __restrict__ feat,
    const float* __restrict__ wn,
    const float* __restrict__ wself,
    const float* __restrict__ bias,
    float*       __restrict__ io,
    float hscale)
{
    __shared__ uint4 wlds[8 * 8 * 64];
    const int t = threadIdx.x;
    for (int idx = t; idx < 8 * 8 * 64; idx += 256) {
        int l  = idx & 63;
        int c  = (idx >> 6) & 7;
        int s  = idx >> 9;
        int o  = c * 16 + (l & 15);
        int kb = s * 32 + (l >> 4) * 8;
        const float* src = (kb < 128) ? (wn + o * 128 + kb)
                                      : (wself + o * 128 + (kb - 128));
        float4 p0 = reinterpret_cast<const float4*>(src)[0];
        float4 p1 = reinterpret_cast<const float4*>(src)[1];
        uint4 w;
        w.x = (unsigned)f2bf(p0.x) | ((unsigned)f2bf(p0.y) << 16);
        w.y = (unsigned)f2bf(p0.z) | ((unsigned)f2bf(p0.w) << 16);
        w.z = (unsigned)f2bf(p1.x) | ((unsigned)f2bf(p1.y) << 16);
        w.w = (unsigned)f2bf(p1.z) | ((unsigned)f2bf(p1.w) << 16);
        wlds[idx] = w;
    }
    __syncthreads();

    const int wave = t >> 6;
    const int l    = t & 63;
    const int l15  = l & 15;
    const int lhi  = l >> 4;

    for (int p = 0; p < 2; ++p) {
        const int rowbase = blockIdx.x * 128 + p * 64 + wave * 16;
        const int arow    = rowbase + l15;
        const float* hrow = io + (long)arow * D + lhi * 8;
        int part = arow / S_SEEDS;
        int idx  = arow - part * S_SEEDS;
        const float* xrow = feat + ((long)part * F_FRONT + idx) * D + lhi * 8;
        f32x4 acc[8] = {};
#pragma unroll
        for (int s = 0; s < 8; ++s) {
            const float* asrc = (s < 4) ? (hrow + s * 32) : (xrow + (s - 4) * 32);
            const float scale = (s < 4) ? hscale : 1.0f;
            float4 a0 = reinterpret_cast<const float4*>(asrc)[0];
            float4 a1 = reinterpret_cast<const float4*>(asrc)[1];
            bf16x8 af;
            af[0] = (short)f2bf(a0.x * scale);
            af[1] = (short)f2bf(a0.y * scale);
            af[2] = (short)f2bf(a0.z * scale);
            af[3] = (short)f2bf(a0.w * scale);
            af[4] = (short)f2bf(a1.x * scale);
            af[5] = (short)f2bf(a1.y * scale);
            af[6] = (short)f2bf(a1.z * scale);
            af[7] = (short)f2bf(a1.w * scale);
#pragma unroll
            for (int c = 0; c < 8; ++c) {
                bf16x8 bf = *reinterpret_cast<const bf16x8*>(&wlds[(s * 8 + c) * 64 + l]);
                acc[c] = __builtin_amdgcn_mfma_f32_16x16x32_bf16(af, bf, acc[c], 0, 0, 0);
            }
        }
#pragma unroll
        for (int c = 0; c < 8; ++c) {
            const int col = c * 16 + l15;
            const float bv = bias[col];
#pragma unroll
            for (int j = 0; j < 4; ++j) {
                const int r = rowbase + lhi * 4 + j;
                io[(long)r * D + col] = acc[c][j] + bv;
            }
        }
    }
}

// Fallback gather writing f32 h (into d_out)
__global__ __launch_bounds__(256) void gather_f32_k(
    const float* __restrict__ feat,
    const int*   __restrict__ cnt,
    const int*   __restrict__ elist,
    float*       __restrict__ h)
{
    const int t   = threadIdx.x;
    const int dst = blockIdx.x * 8 + (t >> 5);
    const int l   = t & 31;
    int deg = cnt[dst];
    if (deg > CAP) deg = CAP;
    const int* el = elist + (long)dst * CAP;
    const float4* F4 = reinterpret_cast<const float4*>(feat);
    f32x4 acc = {0.f, 0.f, 0.f, 0.f};
    for (int e = 0; e < deg; ++e) {
        float4 v = F4[(long)el[e] * 32 + l];
        acc[0] += v.x; acc[1] += v.y; acc[2] += v.z; acc[3] += v.w;
    }
    float4 r;
    r.x = acc[0] * (1.0f / FANOUT);
    r.y = acc[1] * (1.0f / FANOUT);
    r.z = acc[2] * (1.0f / FANOUT);
    r.w = acc[3] * (1.0f / FANOUT);
    reinterpret_cast<float4*>(h)[(long)dst * 32 + l] = r;
}

// Last-resort atomic scatter (round-1 path)
__global__ __launch_bounds__(256) void scatter_k(
    const float* __restrict__ feat,
    const int*   __restrict__ coo_row,
    const int*   __restrict__ coo_col,
    float*       __restrict__ hsum)
{
    unsigned g = blockIdx.x * 256u + threadIdx.x;
    unsigned e = g >> 5;
    unsigned l = g & 31u;
    unsigned part = e / E_EDGES;
    unsigned dst  = part * S_SEEDS + (unsigned)coo_row[e];
    unsigned long src = (unsigned long)part * F_FRONT + (unsigned)coo_col[e];
    float4 v = reinterpret_cast<const float4*>(feat)[src * 32u + l];
    float* o = hsum + (unsigned long)dst * D + l * 4u;
    atomicAdd(o + 0, v.x);
    atomicAdd(o + 1, v.y);
    atomicAdd(o + 2, v.z);
    atomicAdd(o + 3, v.w);
}

extern "C" void kernel_launch(void* const* d_in, const int* in_sizes, int n_in,
                              void* d_out, int out_size, void* d_ws, size_t ws_size,
                              hipStream_t stream) {
    const float* feat    = (const float*)d_in[0];
    const int*   coo_row = (const int*)d_in[1];
    const int*   coo_col = (const int*)d_in[2];
    const float* wn      = (const float*)d_in[3];
    const float* wself   = (const float*)d_in[4];
    const float* bias    = (const float*)d_in[5];
    float*       out     = (float*)d_out;

    const size_t csr_bytes = (size_t)M_ROWS * sizeof(int)
                           + (size_t)M_ROWS * CAP * sizeof(int);
    const size_t hb_bytes  = (size_t)M_ROWS * D * sizeof(unsigned short);

    if (ws_size >= csr_bytes + hb_bytes) {
        int* cnt   = (int*)d_ws;
        int* elist = cnt + M_ROWS;
        unsigned short* hb = (unsigned short*)(elist + (size_t)M_ROWS * CAP);

        hipMemsetAsync(cnt, 0, (size_t)M_ROWS * sizeof(int), stream);
        fill_k<<<N_EDGES / 1024, 256, 0, stream>>>(coo_row, coo_col, cnt, elist);
        gather_k<<<M_ROWS / 8, 256, 0, stream>>>(feat, cnt, elist, hb);
        finish_k<<<M_ROWS / 64, 256, 0, stream>>>(feat, hb, wn, wself, bias, out);
    } else if (ws_size >= csr_bytes) {
        int* cnt   = (int*)d_ws;
        int* elist = cnt + M_ROWS;
        hipMemsetAsync(cnt, 0, (size_t)M_ROWS * sizeof(int), stream);
        fill_k<<<N_EDGES / 1024, 256, 0, stream>>>(coo_row, coo_col, cnt, elist);
        gather_f32_k<<<M_ROWS / 8, 256, 0, stream>>>(feat, cnt, elist, out);
        finish_f32_k<<<M_ROWS / 128, 256, 0, stream>>>(feat, wn, wself, bias, out, 1.0f);
    } else {
        hipMemsetAsync(out, 0, (size_t)M_ROWS * D * sizeof(float), stream);
        scatter_k<<<N_EDGES / 8, 256, 0, stream>>>(feat, coo_row, coo_col, out);
        finish_f32_k<<<M_ROWS / 128, 256, 0, stream>>>(feat, wn, wself, bias, out,
                                                       1.0f / FANOUT);
    }
}

// Round 6
// 176.927 us; speedup vs baseline: 1.0992x; 1.0992x over previous
//
#include <hip/hip_runtime.h>
#include <hip/hip_bf16.h>

// Problem constants (match reference)
#define WORLD   4
#define S_SEEDS 16000
#define FANOUT  16
#define F_FRONT (S_SEEDS * (FANOUT + 1))   // 272000 frontier rows / partition
#define E_EDGES (S_SEEDS * FANOUT)         // 256000 edges / partition
#define D       128
#define M_ROWS  (WORLD * S_SEEDS)          // 64000 output rows
#define N_EDGES (WORLD * E_EDGES)          // 1024000 edges total
#define CAP     64                         // per-dst bucket capacity (Poisson(16): P(>64)~3e-20)

typedef __attribute__((ext_vector_type(8))) short bf16x8;
typedef __attribute__((ext_vector_type(4))) float f32x4;
typedef __attribute__((ext_vector_type(4))) unsigned short u16x4;

__device__ __forceinline__ unsigned short f2bf(float f) {
    union { float f; unsigned u; } v; v.f = f;
    unsigned r = v.u + 0x7FFFu + ((v.u >> 16) & 1u);   // RNE
    return (unsigned short)(r >> 16);
}

// ---------------------------------------------------------------------------
// Kernel 0: weight pre-pack. Converts Wn|Ws (fp32, row-major [128][128]) to
// bf16 MFMA B-fragments in the exact LDS order finish_k uses:
//   wpk[(s*8 + c)*64 + l] = fragment for kstep s, ctile c, lane l.
// Runs once, 16 blocks x 256 thr, one entry per thread.
// ---------------------------------------------------------------------------
__global__ __launch_bounds__(256) void pack_k(
    const float* __restrict__ wn,
    const float* __restrict__ wself,
    uint4*       __restrict__ wpk)
{
    int idx = blockIdx.x * 256 + threadIdx.x;   // 0 .. 4095
    int l  = idx & 63;
    int c  = (idx >> 6) & 7;
    int s  = idx >> 9;
    int o  = c * 16 + (l & 15);          // output channel (B col)
    int kb = s * 32 + (l >> 4) * 8;      // k base (8 contiguous k per lane)
    const float* src = (kb < 128) ? (wn + o * 128 + kb)
                                  : (wself + o * 128 + (kb - 128));
    float4 p0 = reinterpret_cast<const float4*>(src)[0];
    float4 p1 = reinterpret_cast<const float4*>(src)[1];
    uint4 w;
    w.x = (unsigned)f2bf(p0.x) | ((unsigned)f2bf(p0.y) << 16);
    w.y = (unsigned)f2bf(p0.z) | ((unsigned)f2bf(p0.w) << 16);
    w.z = (unsigned)f2bf(p1.x) | ((unsigned)f2bf(p1.y) << 16);
    w.w = (unsigned)f2bf(p1.z) | ((unsigned)f2bf(p1.w) << 16);
    wpk[idx] = w;
}

// ---------------------------------------------------------------------------
// Kernel 1a: bucket fill. One thread per edge; int atomic gets the slot.
// (round-3 configuration — quad version regressed)
// ---------------------------------------------------------------------------
__global__ __launch_bounds__(256) void fill_k(
    const int* __restrict__ coo_row,
    const int* __restrict__ coo_col,
    int*       __restrict__ cnt,
    int*       __restrict__ elist)
{
    unsigned e = blockIdx.x * 256u + threadIdx.x;
    unsigned part = e / E_EDGES;
    unsigned dst  = part * S_SEEDS + (unsigned)coo_row[e];
    unsigned src  = part * F_FRONT + (unsigned)coo_col[e];
    int slot = atomicAdd(&cnt[dst], 1);
    if (slot < CAP)
        elist[(unsigned long)dst * CAP + slot] = (int)src;
}

// ---------------------------------------------------------------------------
// Kernel 1b: per-dst gather (round-3 variant — best measured, 182.7 us).
// Half-wave (32 lanes) per dst row; lane owns a fixed float4 channel slice.
// Indices prefetched via int4; chunks of 16 independent row loads. Mean
// written as bf16 (halves h traffic).
// ---------------------------------------------------------------------------
__global__ __launch_bounds__(256) void gather_k(
    const float* __restrict__ feat,
    const int*   __restrict__ cnt,
    const int*   __restrict__ elist,
    unsigned short* __restrict__ hb)   // [M_ROWS][D] bf16
{
    const int t   = threadIdx.x;
    const int dst = blockIdx.x * 8 + (t >> 5);
    const int l   = t & 31;

    int deg = cnt[dst];
    if (deg > CAP) deg = CAP;   // safety (never expected)
    const int* el = elist + (long)dst * CAP;
    const float4* F4 = reinterpret_cast<const float4*>(feat);

    f32x4 accA = {0.f, 0.f, 0.f, 0.f};
    f32x4 accB = {0.f, 0.f, 0.f, 0.f};

    int e = 0;
    for (; e + 16 <= deg; e += 16) {
        int4 i0 = *reinterpret_cast<const int4*>(el + e);
        int4 i1 = *reinterpret_cast<const int4*>(el + e + 4);
        int4 i2 = *reinterpret_cast<const int4*>(el + e + 8);
        int4 i3 = *reinterpret_cast<const int4*>(el + e + 12);
        float4 v0  = F4[(long)i0.x * 32 + l];
        float4 v1  = F4[(long)i0.y * 32 + l];
        float4 v2  = F4[(long)i0.z * 32 + l];
        float4 v3  = F4[(long)i0.w * 32 + l];
        float4 v4  = F4[(long)i1.x * 32 + l];
        float4 v5  = F4[(long)i1.y * 32 + l];
        float4 v6  = F4[(long)i1.z * 32 + l];
        float4 v7  = F4[(long)i1.w * 32 + l];
        float4 v8  = F4[(long)i2.x * 32 + l];
        float4 v9  = F4[(long)i2.y * 32 + l];
        float4 v10 = F4[(long)i2.z * 32 + l];
        float4 v11 = F4[(long)i2.w * 32 + l];
        float4 v12 = F4[(long)i3.x * 32 + l];
        float4 v13 = F4[(long)i3.y * 32 + l];
        float4 v14 = F4[(long)i3.z * 32 + l];
        float4 v15 = F4[(long)i3.w * 32 + l];
        accA[0] += v0.x + v2.x + v4.x + v6.x + v8.x + v10.x + v12.x + v14.x;
        accA[1] += v0.y + v2.y + v4.y + v6.y + v8.y + v10.y + v12.y + v14.y;
        accA[2] += v0.z + v2.z + v4.z + v6.z + v8.z + v10.z + v12.z + v14.z;
        accA[3] += v0.w + v2.w + v4.w + v6.w + v8.w + v10.w + v12.w + v14.w;
        accB[0] += v1.x + v3.x + v5.x + v7.x + v9.x + v11.x + v13.x + v15.x;
        accB[1] += v1.y + v3.y + v5.y + v7.y + v9.y + v11.y + v13.y + v15.y;
        accB[2] += v1.z + v3.z + v5.z + v7.z + v9.z + v11.z + v13.z + v15.z;
        accB[3] += v1.w + v3.w + v5.w + v7.w + v9.w + v11.w + v13.w + v15.w;
    }
    for (; e + 4 <= deg; e += 4) {
        int4 i0 = *reinterpret_cast<const int4*>(el + e);
        float4 v0 = F4[(long)i0.x * 32 + l];
        float4 v1 = F4[(long)i0.y * 32 + l];
        float4 v2 = F4[(long)i0.z * 32 + l];
        float4 v3 = F4[(long)i0.w * 32 + l];
        accA[0] += v0.x + v2.x; accA[1] += v0.y + v2.y;
        accA[2] += v0.z + v2.z; accA[3] += v0.w + v2.w;
        accB[0] += v1.x + v3.x; accB[1] += v1.y + v3.y;
        accB[2] += v1.z + v3.z; accB[3] += v1.w + v3.w;
    }
    for (; e < deg; ++e) {
        float4 v = F4[(long)el[e] * 32 + l];
        accA[0] += v.x; accA[1] += v.y; accA[2] += v.z; accA[3] += v.w;
    }

    u16x4 r;
    r.x = f2bf((accA[0] + accB[0]) * (1.0f / FANOUT));
    r.y = f2bf((accA[1] + accB[1]) * (1.0f / FANOUT));
    r.z = f2bf((accA[2] + accB[2]) * (1.0f / FANOUT));
    r.w = f2bf((accA[3] + accB[3]) * (1.0f / FANOUT));
    *reinterpret_cast<u16x4*>(hb + (long)dst * D + l * 4) = r;
}

// ---------------------------------------------------------------------------
// Kernel 2: fused finish (round-3 structure: 500 blocks x 2 passes):
//   out[r] = hb[r] @ Wn^T + feat_dst[r] @ Ws^T + b
// Weights arrive PRE-PACKED (bf16 fragment order) -> staging is a pure
// 64 KB uint4 copy, no converts.
// ---------------------------------------------------------------------------
__global__ __launch_bounds__(256) void finish_k(
    const float*          __restrict__ feat,
    const unsigned short* __restrict__ hb,
    const uint4*          __restrict__ wpk,
    const float*          __restrict__ bias,
    float*                __restrict__ out)
{
    // [kstep 8][ctile 8][lane 64] -> one 16B bf16x8 B-fragment per entry
    __shared__ uint4 wlds[8 * 8 * 64];

    const int t = threadIdx.x;

    // ---- stage pre-packed weights: 16 coalesced uint4 loads per thread ----
#pragma unroll
    for (int i = 0; i < 16; ++i) {
        int idx = i * 256 + t;
        wlds[idx] = wpk[idx];
    }
    __syncthreads();

    const int wave = t >> 6;
    const int l    = t & 63;
    const int l15  = l & 15;
    const int lhi  = l >> 4;

    for (int p = 0; p < 2; ++p) {
        const int rowbase = blockIdx.x * 128 + p * 64 + wave * 16;
        const int arow    = rowbase + l15;          // A row this lane loads

        const unsigned short* hrow = hb + (long)arow * D + lhi * 8;
        int part = arow / S_SEEDS;
        int idx  = arow - part * S_SEEDS;
        const float* xrow = feat + ((long)part * F_FRONT + idx) * D + lhi * 8;

        f32x4 acc[8] = {};

#pragma unroll
        for (int s = 0; s < 8; ++s) {
            bf16x8 af;
            if (s < 4) {
                af = *reinterpret_cast<const bf16x8*>(hrow + s * 32);
            } else {
                const float* asrc = xrow + (s - 4) * 32;
                float4 a0 = reinterpret_cast<const float4*>(asrc)[0];
                float4 a1 = reinterpret_cast<const float4*>(asrc)[1];
                af[0] = (short)f2bf(a0.x);
                af[1] = (short)f2bf(a0.y);
                af[2] = (short)f2bf(a0.z);
                af[3] = (short)f2bf(a0.w);
                af[4] = (short)f2bf(a1.x);
                af[5] = (short)f2bf(a1.y);
                af[6] = (short)f2bf(a1.z);
                af[7] = (short)f2bf(a1.w);
            }
#pragma unroll
            for (int c = 0; c < 8; ++c) {
                bf16x8 bf = *reinterpret_cast<const bf16x8*>(&wlds[(s * 8 + c) * 64 + l]);
                acc[c] = __builtin_amdgcn_mfma_f32_16x16x32_bf16(af, bf, acc[c], 0, 0, 0);
            }
        }

        // C/D layout (verified m89): col = lane&15, row = (lane>>4)*4 + reg
#pragma unroll
        for (int c = 0; c < 8; ++c) {
            const int col = c * 16 + l15;
            const float bv = bias[col];
#pragma unroll
            for (int j = 0; j < 4; ++j) {
                const int r = rowbase + lhi * 4 + j;
                out[(long)r * D + col] = acc[c][j] + bv;
            }
        }
    }
}

// ---------------------------------------------------------------------------
// Fallback finish (stages fp32 weights itself; h in d_out as f32) — small-ws.
// ---------------------------------------------------------------------------
__global__ __launch_bounds__(256) void finish_f32_k(
    const float* __restrict__ feat,
    const float* __restrict__ wn,
    const float* __restrict__ wself,
    const float* __restrict__ bias,
    float*       __restrict__ io,
    float hscale)
{
    __shared__ uint4 wlds[8 * 8 * 64];
    const int t = threadIdx.x;
    for (int idx = t; idx < 8 * 8 * 64; idx += 256) {
        int l  = idx & 63;
        int c  = (idx >> 6) & 7;
        int s  = idx >> 9;
        int o  = c * 16 + (l & 15);
        int kb = s * 32 + (l >> 4) * 8;
        const float* src = (kb < 128) ? (wn + o * 128 + kb)
                                      : (wself + o * 128 + (kb - 128));
        float4 p0 = reinterpret_cast<const float4*>(src)[0];
        float4 p1 = reinterpret_cast<const float4*>(src)[1];
        uint4 w;
        w.x = (unsigned)f2bf(p0.x) | ((unsigned)f2bf(p0.y) << 16);
        w.y = (unsigned)f2bf(p0.z) | ((unsigned)f2bf(p0.w) << 16);
        w.z = (unsigned)f2bf(p1.x) | ((unsigned)f2bf(p1.y) << 16);
        w.w = (unsigned)f2bf(p1.z) | ((unsigned)f2bf(p1.w) << 16);
        wlds[idx] = w;
    }
    __syncthreads();

    const int wave = t >> 6;
    const int l    = t & 63;
    const int l15  = l & 15;
    const int lhi  = l >> 4;

    for (int p = 0; p < 2; ++p) {
        const int rowbase = blockIdx.x * 128 + p * 64 + wave * 16;
        const int arow    = rowbase + l15;
        const float* hrow = io + (long)arow * D + lhi * 8;
        int part = arow / S_SEEDS;
        int idx  = arow - part * S_SEEDS;
        const float* xrow = feat + ((long)part * F_FRONT + idx) * D + lhi * 8;
        f32x4 acc[8] = {};
#pragma unroll
        for (int s = 0; s < 8; ++s) {
            const float* asrc = (s < 4) ? (hrow + s * 32) : (xrow + (s - 4) * 32);
            const float scale = (s < 4) ? hscale : 1.0f;
            float4 a0 = reinterpret_cast<const float4*>(asrc)[0];
            float4 a1 = reinterpret_cast<const float4*>(asrc)[1];
            bf16x8 af;
            af[0] = (short)f2bf(a0.x * scale);
            af[1] = (short)f2bf(a0.y * scale);
            af[2] = (short)f2bf(a0.z * scale);
            af[3] = (short)f2bf(a0.w * scale);
            af[4] = (short)f2bf(a1.x * scale);
            af[5] = (short)f2bf(a1.y * scale);
            af[6] = (short)f2bf(a1.z * scale);
            af[7] = (short)f2bf(a1.w * scale);
#pragma unroll
            for (int c = 0; c < 8; ++c) {
                bf16x8 bf = *reinterpret_cast<const bf16x8*>(&wlds[(s * 8 + c) * 64 + l]);
                acc[c] = __builtin_amdgcn_mfma_f32_16x16x32_bf16(af, bf, acc[c], 0, 0, 0);
            }
        }
#pragma unroll
        for (int c = 0; c < 8; ++c) {
            const int col = c * 16 + l15;
            const float bv = bias[col];
#pragma unroll
            for (int j = 0; j < 4; ++j) {
                const int r = rowbase + lhi * 4 + j;
                io[(long)r * D + col] = acc[c][j] + bv;
            }
        }
    }
}

// Fallback gather writing f32 h (into d_out)
__global__ __launch_bounds__(256) void gather_f32_k(
    const float* __restrict__ feat,
    const int*   __restrict__ cnt,
    const int*   __restrict__ elist,
    float*       __restrict__ h)
{
    const int t   = threadIdx.x;
    const int dst = blockIdx.x * 8 + (t >> 5);
    const int l   = t & 31;
    int deg = cnt[dst];
    if (deg > CAP) deg = CAP;
    const int* el = elist + (long)dst * CAP;
    const float4* F4 = reinterpret_cast<const float4*>(feat);
    f32x4 acc = {0.f, 0.f, 0.f, 0.f};
    for (int e = 0; e < deg; ++e) {
        float4 v = F4[(long)el[e] * 32 + l];
        acc[0] += v.x; acc[1] += v.y; acc[2] += v.z; acc[3] += v.w;
    }
    float4 r;
    r.x = acc[0] * (1.0f / FANOUT);
    r.y = acc[1] * (1.0f / FANOUT);
    r.z = acc[2] * (1.0f / FANOUT);
    r.w = acc[3] * (1.0f / FANOUT);
    reinterpret_cast<float4*>(h)[(long)dst * 32 + l] = r;
}

// Last-resort atomic scatter (round-1 path)
__global__ __launch_bounds__(256) void scatter_k(
    const float* __restrict__ feat,
    const int*   __restrict__ coo_row,
    const int*   __restrict__ coo_col,
    float*       __restrict__ hsum)
{
    unsigned g = blockIdx.x * 256u + threadIdx.x;
    unsigned e = g >> 5;
    unsigned l = g & 31u;
    unsigned part = e / E_EDGES;
    unsigned dst  = part * S_SEEDS + (unsigned)coo_row[e];
    unsigned long src = (unsigned long)part * F_FRONT + (unsigned)coo_col[e];
    float4 v = reinterpret_cast<const float4*>(feat)[src * 32u + l];
    float* o = hsum + (unsigned long)dst * D + l * 4u;
    atomicAdd(o + 0, v.x);
    atomicAdd(o + 1, v.y);
    atomicAdd(o + 2, v.z);
    atomicAdd(o + 3, v.w);
}

extern "C" void kernel_launch(void* const* d_in, const int* in_sizes, int n_in,
                              void* d_out, int out_size, void* d_ws, size_t ws_size,
                              hipStream_t stream) {
    const float* feat    = (const float*)d_in[0];
    const int*   coo_row = (const int*)d_in[1];
    const int*   coo_col = (const int*)d_in[2];
    const float* wn      = (const float*)d_in[3];
    const float* wself   = (const float*)d_in[4];
    const float* bias    = (const float*)d_in[5];
    float*       out     = (float*)d_out;

    const size_t csr_bytes = (size_t)M_ROWS * sizeof(int)
                           + (size_t)M_ROWS * CAP * sizeof(int);
    const size_t hb_bytes  = (size_t)M_ROWS * D * sizeof(unsigned short);
    const size_t wpk_bytes = 8 * 8 * 64 * sizeof(uint4);   // 64 KB

    if (ws_size >= csr_bytes + hb_bytes + wpk_bytes) {
        int* cnt   = (int*)d_ws;
        int* elist = cnt + M_ROWS;
        unsigned short* hb = (unsigned short*)(elist + (size_t)M_ROWS * CAP);
        uint4* wpk = (uint4*)(hb + (size_t)M_ROWS * D);

        hipMemsetAsync(cnt, 0, (size_t)M_ROWS * sizeof(int), stream);
        pack_k<<<16, 256, 0, stream>>>(wn, wself, wpk);
        fill_k<<<N_EDGES / 256, 256, 0, stream>>>(coo_row, coo_col, cnt, elist);
        gather_k<<<M_ROWS / 8, 256, 0, stream>>>(feat, cnt, elist, hb);
        finish_k<<<M_ROWS / 128, 256, 0, stream>>>(feat, hb, wpk, bias, out);
    } else if (ws_size >= csr_bytes) {
        int* cnt   = (int*)d_ws;
        int* elist = cnt + M_ROWS;
        hipMemsetAsync(cnt, 0, (size_t)M_ROWS * sizeof(int), stream);
        fill_k<<<N_EDGES / 256, 256, 0, stream>>>(coo_row, coo_col, cnt, elist);
        gather_f32_k<<<M_ROWS / 8, 256, 0, stream>>>(feat, cnt, elist, out);
        finish_f32_k<<<M_ROWS / 128, 256, 0, stream>>>(feat, wn, wself, bias, out, 1.0f);
    } else {
        hipMemsetAsync(out, 0, (size_t)M_ROWS * D * sizeof(float), stream);
        scatter_k<<<N_EDGES / 8, 256, 0, stream>>>(feat, coo_row, coo_col, out);
        finish_f32_k<<<M_ROWS / 128, 256, 0, stream>>>(feat, wn, wself, bias, out,
                                                       1.0f / FANOUT);
    }
}